// Round 2
// baseline (273.774 us; speedup 1.0000x reference)
//
#include <hip/hip_runtime.h>
#include <math.h>

#define DMODEL 256
#define NH 8
#define DH 32
#define NEG_INF -1e30f

// ======================================================================
// GEMM building blocks: 128 threads, 32x64 tile, micro 4x4, full-K=256
// LDS: As[256][36] (A transposed [k][m], stride 36 keeps float4 align),
//      Bs[256][64]. One __syncthreads per kernel, no mid-loop barriers.
// ======================================================================

__device__ __forceinline__ void stage_B64(const float* __restrict__ Bw, int ldb, int n0,
                                          float (*__restrict__ Bs)[64])
{
  int tid = threadIdx.x;
#pragma unroll
  for (int i = 0; i < 32; ++i) {
    int idx = tid + 128 * i;            // 0..4095 float4s
    int k = idx >> 4, c = (idx & 15) << 2;
    *(float4*)&Bs[k][c] = *(const float4*)(Bw + (size_t)k * ldb + n0 + c);
  }
}

__device__ __forceinline__ void stage_A_copy(const float* __restrict__ A, int lda,
                                             int m0, int kbeg,
                                             float (*__restrict__ As)[36])
{
  int tid = threadIdx.x;
  int r = tid >> 2, p = tid & 3;        // row 0..31, quarter 0..3
  const float* row = A + (size_t)(m0 + r) * lda + kbeg + p * 64;
#pragma unroll
  for (int j = 0; j < 16; ++j) {
    float4 v = *(const float4*)(row + j * 4);
    int k = p * 64 + j * 4;
    As[k + 0][r] = v.x; As[k + 1][r] = v.y; As[k + 2][r] = v.z; As[k + 3][r] = v.w;
  }
}

// LayerNorm fused into A-staging: each thread owns 64 cols of one row,
// 4-lane shuffle tree completes the 256-col reduction.
__device__ __forceinline__ void stage_A_ln(const float* __restrict__ Xsrc, int m0,
                                           const float* __restrict__ g,
                                           const float* __restrict__ b,
                                           float (*__restrict__ As)[36])
{
  int tid = threadIdx.x;
  int r = tid >> 2, p = tid & 3;
  const float* row = Xsrc + (size_t)(m0 + r) * DMODEL + p * 64;
  float4 v[16];
  float s = 0.f, ss = 0.f;
#pragma unroll
  for (int j = 0; j < 16; ++j) {
    v[j] = *(const float4*)(row + j * 4);
    s  += v[j].x + v[j].y + v[j].z + v[j].w;
    ss += v[j].x * v[j].x + v[j].y * v[j].y + v[j].z * v[j].z + v[j].w * v[j].w;
  }
  s  += __shfl_xor(s, 1);  s  += __shfl_xor(s, 2);
  ss += __shfl_xor(ss, 1); ss += __shfl_xor(ss, 2);
  float mean = s * (1.0f / 256.0f);
  float var  = ss * (1.0f / 256.0f) - mean * mean;
  float rstd = rsqrtf(var + 1e-5f);
#pragma unroll
  for (int j = 0; j < 16; ++j) {
    float4 gg = *(const float4*)(g + p * 64 + j * 4);
    float4 bb = *(const float4*)(b + p * 64 + j * 4);
    int k = p * 64 + j * 4;
    As[k + 0][r] = (v[j].x - mean) * rstd * gg.x + bb.x;
    As[k + 1][r] = (v[j].y - mean) * rstd * gg.y + bb.y;
    As[k + 2][r] = (v[j].z - mean) * rstd * gg.z + bb.z;
    As[k + 3][r] = (v[j].w - mean) * rstd * gg.w + bb.w;
  }
}

__device__ __forceinline__ void gemm_compute(const float (*__restrict__ As)[36],
                                             const float (*__restrict__ Bs)[64],
                                             float acc[4][4])
{
  int tid = threadIdx.x;
  int tx = tid & 15, ty = tid >> 4;     // tx: col/4 (0..15), ty: row/4 (0..7)
#pragma unroll 8
  for (int k = 0; k < 256; ++k) {
    float4 a  = *(const float4*)&As[k][ty * 4];
    float4 bv = *(const float4*)&Bs[k][tx * 4];
    acc[0][0] = fmaf(a.x, bv.x, acc[0][0]); acc[0][1] = fmaf(a.x, bv.y, acc[0][1]);
    acc[0][2] = fmaf(a.x, bv.z, acc[0][2]); acc[0][3] = fmaf(a.x, bv.w, acc[0][3]);
    acc[1][0] = fmaf(a.y, bv.x, acc[1][0]); acc[1][1] = fmaf(a.y, bv.y, acc[1][1]);
    acc[1][2] = fmaf(a.y, bv.z, acc[1][2]); acc[1][3] = fmaf(a.y, bv.w, acc[1][3]);
    acc[2][0] = fmaf(a.z, bv.x, acc[2][0]); acc[2][1] = fmaf(a.z, bv.y, acc[2][1]);
    acc[2][2] = fmaf(a.z, bv.z, acc[2][2]); acc[2][3] = fmaf(a.z, bv.w, acc[2][3]);
    acc[3][0] = fmaf(a.w, bv.x, acc[3][0]); acc[3][1] = fmaf(a.w, bv.y, acc[3][1]);
    acc[3][2] = fmaf(a.w, bv.z, acc[3][2]); acc[3][3] = fmaf(a.w, bv.w, acc[3][3]);
  }
}

// ---------- QKV with fused LayerNorm: grid (4,16,3) x 128 ----------
__global__ __launch_bounds__(128) void qkv_kernel(
    const float* __restrict__ srcin, const float* __restrict__ tgt,
    const float* __restrict__ ln1g, const float* __restrict__ ln1b,
    const float* __restrict__ lntg, const float* __restrict__ lntb,
    const float* __restrict__ wq, const float* __restrict__ wk, const float* __restrict__ wv,
    const float* __restrict__ bq, const float* __restrict__ bk, const float* __restrict__ bv,
    float* __restrict__ Qb, float* __restrict__ Kb, float* __restrict__ Vb)
{
  __shared__ __align__(16) float As[256][36];
  __shared__ __align__(16) float Bs[256][64];
  int z = blockIdx.z;
  int m0 = blockIdx.y * 32, n0 = blockIdx.x * 64;
  const float* Bw = (z == 0) ? wq : (z == 1) ? wk : wv;
  stage_B64(Bw, DMODEL, n0, Bs);
  if (z == 0) stage_A_ln(srcin, m0, ln1g, ln1b, As);
  else        stage_A_ln(tgt,   m0, lntg, lntb, As);
  __syncthreads();
  float acc[4][4] = {};
  gemm_compute(As, Bs, acc);
  const float* bias = (z == 0) ? bq : (z == 1) ? bk : bv;
  int tid = threadIdx.x, tx = tid & 15, ty = tid >> 4;
  int c0 = n0 + tx * 4;
  float4 bias4 = *(const float4*)(bias + c0);
  const float scale = 0.1767766952966369f;  // 1/sqrt(32)
#pragma unroll
  for (int i = 0; i < 4; ++i) {
    int m = m0 + ty * 4 + i;
    float4 r;
    r.x = acc[i][0] + bias4.x;
    r.y = acc[i][1] + bias4.y;
    r.z = acc[i][2] + bias4.z;
    r.w = acc[i][3] + bias4.w;
    if (z == 0) {
      r.x *= scale; r.y *= scale; r.z *= scale; r.w *= scale;
      *(float4*)&Qb[m * DMODEL + c0] = r;
    } else {
      int b = m >> 8, t = m & 255, h = c0 >> 5, d0 = c0 & 31;
      float* dst = ((z == 1) ? Kb : Vb) + (size_t)(b * NH + h) * 8192 + t * DH + d0;
      *(float4*)dst = r;
    }
  }
}

// ---------- wo GEMM, full-K, residual (src + bo) epilogue : grid (4,16) ----------
__global__ __launch_bounds__(128) void wo_kernel(
    const float* __restrict__ AO, const float* __restrict__ wo,
    const float* __restrict__ srcin, const float* __restrict__ bo,
    float* __restrict__ X)
{
  __shared__ __align__(16) float As[256][36];
  __shared__ __align__(16) float Bs[256][64];
  int m0 = blockIdx.y * 32, n0 = blockIdx.x * 64;
  stage_B64(wo, DMODEL, n0, Bs);
  stage_A_copy(AO, DMODEL, m0, 0, As);
  __syncthreads();
  float acc[4][4] = {};
  gemm_compute(As, Bs, acc);
  int tid = threadIdx.x, tx = tid & 15, ty = tid >> 4;
  int c0 = n0 + tx * 4;
  float4 bov = *(const float4*)(bo + c0);
#pragma unroll
  for (int i = 0; i < 4; ++i) {
    int m = m0 + ty * 4 + i;
    float4 sv = *(const float4*)(srcin + (size_t)m * DMODEL + c0);
    float4 r;
    r.x = sv.x + bov.x + acc[i][0];
    r.y = sv.y + bov.y + acc[i][1];
    r.z = sv.z + bov.z + acc[i][2];
    r.w = sv.w + bov.w + acc[i][3];
    *(float4*)&X[(size_t)m * DMODEL + c0] = r;
  }
}

// ---------- FF1 with fused LN2 + ReLU; x==0 blocks write ff2's out-init ----------
__global__ __launch_bounds__(128) void ff1_kernel(
    const float* __restrict__ X, const float* __restrict__ ln2g, const float* __restrict__ ln2b,
    const float* __restrict__ w1, const float* __restrict__ b1,
    const float* __restrict__ b2, const int* __restrict__ smask,
    float* __restrict__ H1, float* __restrict__ outb)
{
  __shared__ __align__(16) float As[256][36];
  __shared__ __align__(16) float Bs[256][64];
  int m0 = blockIdx.y * 32, n0 = blockIdx.x * 64;
  stage_B64(w1, 1024, n0, Bs);
  stage_A_ln(X, m0, ln2g, ln2b, As);
  if (blockIdx.x == 0) {   // out-init = mask * (X + b2), one block per row-group
    int tid = threadIdx.x;
    int r = tid >> 2, p = tid & 3;
    int m = m0 + r;
    float mm = (smask[m] != 0) ? 0.0f : 1.0f;
#pragma unroll
    for (int j = 0; j < 16; ++j) {
      float4 xv  = *(const float4*)(X  + (size_t)m * DMODEL + p * 64 + j * 4);
      float4 b2v = *(const float4*)(b2 + p * 64 + j * 4);
      float4 o;
      o.x = mm * (xv.x + b2v.x); o.y = mm * (xv.y + b2v.y);
      o.z = mm * (xv.z + b2v.z); o.w = mm * (xv.w + b2v.w);
      *(float4*)(outb + (size_t)m * DMODEL + p * 64 + j * 4) = o;
    }
  }
  __syncthreads();
  float acc[4][4] = {};
  gemm_compute(As, Bs, acc);
  int tid = threadIdx.x, tx = tid & 15, ty = tid >> 4;
  int c0 = n0 + tx * 4;
  float4 b1v = *(const float4*)(b1 + c0);
#pragma unroll
  for (int i = 0; i < 4; ++i) {
    int m = m0 + ty * 4 + i;
    float4 r;
    r.x = fmaxf(acc[i][0] + b1v.x, 0.0f);
    r.y = fmaxf(acc[i][1] + b1v.y, 0.0f);
    r.z = fmaxf(acc[i][2] + b1v.z, 0.0f);
    r.w = fmaxf(acc[i][3] + b1v.w, 0.0f);
    *(float4*)&H1[(size_t)m * 1024 + c0] = r;
  }
}

// ---------- FF2 split-K=4 GEMM, masked atomic accumulate : grid (4,16,4) ----------
__global__ __launch_bounds__(128) void ff2_kernel(
    const float* __restrict__ H1, const float* __restrict__ w2,
    const int* __restrict__ smask, float* __restrict__ outb)
{
  __shared__ __align__(16) float As[256][36];
  __shared__ __align__(16) float Bs[256][64];
  int m0 = blockIdx.y * 32, n0 = blockIdx.x * 64;
  int kbeg = blockIdx.z * 256;
  stage_B64(w2 + (size_t)kbeg * DMODEL, DMODEL, n0, Bs);
  stage_A_copy(H1, 1024, m0, kbeg, As);
  __syncthreads();
  float acc[4][4] = {};
  gemm_compute(As, Bs, acc);
  int tid = threadIdx.x, tx = tid & 15, ty = tid >> 4;
  int c0 = n0 + tx * 4;
#pragma unroll
  for (int i = 0; i < 4; ++i) {
    int m = m0 + ty * 4 + i;
    if (smask[m] == 0) {   // masked rows stay 0 (init already 0) — skip atomics
      atomicAdd(&outb[(size_t)m * DMODEL + c0 + 0], acc[i][0]);
      atomicAdd(&outb[(size_t)m * DMODEL + c0 + 1], acc[i][1]);
      atomicAdd(&outb[(size_t)m * DMODEL + c0 + 2], acc[i][2]);
      atomicAdd(&outb[(size_t)m * DMODEL + c0 + 3], acc[i][3]);
    }
  }
}

// ---------- attention: unchanged from verified version ----------
__global__ __launch_bounds__(256) void attn_kernel(
    const float* __restrict__ Qb, const float* __restrict__ Kb, const float* __restrict__ Vb,
    const float* __restrict__ rpe, const int* __restrict__ tmask,
    const float* __restrict__ wrl, const float* __restrict__ brl,
    float* __restrict__ AO)
{
  __shared__ float Ks[256][32];
  __shared__ float Vt[32][260];
  __shared__ float ps[4][256];
  __shared__ float qs[16][32];
  __shared__ float wks[5][32];   // wr_k rows j=0..3, row4 = br_k  (for head h)
  __shared__ float wvs[5][32];   // wr_v rows j=0..3, row4 = br_v
  int bid = blockIdx.x;
  int b = bid >> 7, h = (bid >> 4) & 7, s0 = (bid & 15) << 4;
  int tid = threadIdx.x;
  const float* Kp = Kb + (size_t)(b * NH + h) * 8192;
  const float* Vp = Vb + (size_t)(b * NH + h) * 8192;
  {
    int t = tid;
    const float4* kr = (const float4*)(Kp + t * DH);
    const float4* vr = (const float4*)(Vp + t * DH);
    int sw = t & 7;
#pragma unroll
    for (int c = 0; c < 8; ++c) {
      float4 k4 = kr[c];
      *(float4*)&Ks[t][(c ^ sw) * 4] = k4;
    }
#pragma unroll
    for (int c = 0; c < 8; ++c) {
      float4 v4 = vr[c];
      Vt[c*4+0][t] = v4.x; Vt[c*4+1][t] = v4.y; Vt[c*4+2][t] = v4.z; Vt[c*4+3][t] = v4.w;
    }
  }
  if (tid < 160) {               // 160 threads cover j=0..4
    int j = tid >> 5, d = tid & 31;
    wks[j][d] = (j < 4) ? wrl[j * 512 + h * DH + d]       : brl[h * DH + d];
    wvs[j][d] = (j < 4) ? wrl[j * 512 + 256 + h * DH + d] : brl[256 + h * DH + d];
  }
  if (tid >= 128) {              // 128 threads load the 16x32 Q tile
    int u = tid - 128;
    int rr = u >> 3, cc = u & 7;
    *(float4*)&qs[rr][cc*4] =
        *(const float4*)&Qb[(b * 256 + s0 + rr) * DMODEL + h * DH + cc * 4];
  }
  __syncthreads();

  int w = tid >> 6, lane = tid & 63;
  int msk[4];
#pragma unroll
  for (int it = 0; it < 4; ++it) msk[it] = tmask[b * 256 + it * 64 + lane];

  for (int i = 0; i < 4; ++i) {
    int sl = w * 4 + i;
    int s = s0 + sl;
    float4 q4[8];
#pragma unroll
    for (int c = 0; c < 8; ++c) q4[c] = *(const float4*)&qs[sl][c * 4];
    float qw[4]; float qbr = 0.0f;
#pragma unroll
    for (int j = 0; j < 4; ++j) {
      float t0 = 0;
#pragma unroll
      for (int c = 0; c < 8; ++c) {
        float4 wv4 = *(const float4*)&wks[j][c * 4];
        t0 += q4[c].x*wv4.x + q4[c].y*wv4.y + q4[c].z*wv4.z + q4[c].w*wv4.w;
      }
      qw[j] = t0;
    }
#pragma unroll
    for (int c = 0; c < 8; ++c) {
      float4 wv4 = *(const float4*)&wks[4][c * 4];
      qbr += q4[c].x*wv4.x + q4[c].y*wv4.y + q4[c].z*wv4.z + q4[c].w*wv4.w;
    }
    const float4* rp4 = (const float4*)(rpe + (size_t)(b * 256 + s) * 1024);
    float sc[4]; float4 rr[4];
#pragma unroll
    for (int it = 0; it < 4; ++it) {
      int t = it * 64 + lane;
      int sw = t & 7;
      float sv = 0;
#pragma unroll
      for (int c = 0; c < 8; ++c) {
        float4 k4 = *(const float4*)&Ks[t][(c ^ sw) * 4];
        sv = fmaf(q4[c].x, k4.x, sv); sv = fmaf(q4[c].y, k4.y, sv);
        sv = fmaf(q4[c].z, k4.z, sv); sv = fmaf(q4[c].w, k4.w, sv);
      }
      float4 rv = rp4[t];
      rr[it] = rv;
      sv += rv.x*qw[0] + rv.y*qw[1] + rv.z*qw[2] + rv.w*qw[3] + qbr;
      if (msk[it] != 0) sv = NEG_INF;
      sc[it] = sv;
    }
    float mval = fmaxf(fmaxf(sc[0], sc[1]), fmaxf(sc[2], sc[3]));
#pragma unroll
    for (int off = 32; off >= 1; off >>= 1) mval = fmaxf(mval, __shfl_xor(mval, off));
    float p[4], lsum = 0;
#pragma unroll
    for (int it = 0; it < 4; ++it) { p[it] = __expf(sc[it] - mval); lsum += p[it]; }
    float wj0 = 0, wj1 = 0, wj2 = 0, wj3 = 0;
#pragma unroll
    for (int it = 0; it < 4; ++it) {
      wj0 = fmaf(p[it], rr[it].x, wj0);
      wj1 = fmaf(p[it], rr[it].y, wj1);
      wj2 = fmaf(p[it], rr[it].z, wj2);
      wj3 = fmaf(p[it], rr[it].w, wj3);
    }
#pragma unroll
    for (int off = 32; off >= 1; off >>= 1) {
      lsum += __shfl_xor(lsum, off);
      wj0 += __shfl_xor(wj0, off);
      wj1 += __shfl_xor(wj1, off);
      wj2 += __shfl_xor(wj2, off);
      wj3 += __shfl_xor(wj3, off);
    }
#pragma unroll
    for (int it = 0; it < 4; ++it) ps[w][it * 64 + lane] = p[it];
    // PV: lane (g,d) accumulates o[d] over its t-half from LDS
    int g = lane >> 5, d = lane & 31;
    float o = 0;
#pragma unroll
    for (int n = 0; n < 32; ++n) {
      int t = g * 128 + n * 4;
      float4 p4 = *(const float4*)&ps[w][t];
      float4 v4 = *(const float4*)&Vt[d][t];
      o += p4.x*v4.x + p4.y*v4.y + p4.z*v4.z + p4.w*v4.w;
    }
    o += __shfl_xor(o, 32);
    float corr = wj0 * wvs[0][d] + wj1 * wvs[1][d] + wj2 * wvs[2][d] + wj3 * wvs[3][d];
    float oval = (o + corr) / lsum + wvs[4][d];
    if (lane < 32) AO[(b * 256 + s) * DMODEL + h * DH + d] = oval;
  }
}

extern "C" void kernel_launch(void* const* d_in, const int* in_sizes, int n_in,
                              void* d_out, int out_size, void* d_ws, size_t ws_size,
                              hipStream_t stream)
{
  const float* src  = (const float*)d_in[0];
  const float* tgt  = (const float*)d_in[1];
  const float* rpe  = (const float*)d_in[2];
  const int*   smask = (const int*)d_in[3];
  const int*   tmask = (const int*)d_in[4];
  const float* ln1g = (const float*)d_in[5];
  const float* ln1b = (const float*)d_in[6];
  const float* lntg = (const float*)d_in[7];
  const float* lntb = (const float*)d_in[8];
  const float* ln2g = (const float*)d_in[9];
  const float* ln2b = (const float*)d_in[10];
  const float* wq = (const float*)d_in[11];
  const float* bq = (const float*)d_in[12];
  const float* wk = (const float*)d_in[13];
  const float* bk = (const float*)d_in[14];
  const float* wv = (const float*)d_in[15];
  const float* bv = (const float*)d_in[16];
  const float* wo = (const float*)d_in[17];
  const float* bo = (const float*)d_in[18];
  const float* wr = (const float*)d_in[19];
  const float* br = (const float*)d_in[20];
  const float* w1 = (const float*)d_in[21];
  const float* b1 = (const float*)d_in[22];
  const float* w2 = (const float*)d_in[23];
  const float* b2 = (const float*)d_in[24];

  float* w    = (float*)d_ws;
  float* Qb   = w;
  float* Kb   = w + 131072;
  float* Vb   = w + 262144;
  float* AO   = w + 393216;
  float* X    = w + 524288;
  float* SRC1 = w + 655360;
  float* H1   = w + 786432;   // 512*1024

  for (int l = 0; l < 2; ++l) {
    const float* srcin = l ? SRC1 : src;
    float* outb = l ? (float*)d_out : SRC1;
    qkv_kernel<<<dim3(4, 16, 3), 128, 0, stream>>>(
        srcin, tgt, ln1g + l*256, ln1b + l*256, lntg + l*256, lntb + l*256,
        wq + l*65536, wk + l*65536, wv + l*65536,
        bq + l*256, bk + l*256, bv + l*256, Qb, Kb, Vb);
    attn_kernel<<<256, 256, 0, stream>>>(Qb, Kb, Vb, rpe, tmask,
                                         wr + l*2048, br + l*512, AO);
    wo_kernel<<<dim3(4, 16), 128, 0, stream>>>(AO, wo + l*65536, srcin, bo + l*256, X);
    ff1_kernel<<<dim3(16, 16), 128, 0, stream>>>(X, ln2g + l*256, ln2b + l*256,
                                                 w1 + l*262144, b1 + l*1024,
                                                 b2 + l*256, smask, H1, outb);
    ff2_kernel<<<dim3(4, 16, 4), 128, 0, stream>>>(H1, w2 + l*262144, smask, outb);
  }
}